// Round 16
// baseline (82.829 us; speedup 1.0000x reference)
//
#include <hip/hip_runtime.h>

typedef __attribute__((ext_vector_type(8))) short s8v;
typedef __attribute__((ext_vector_type(4))) short s4v;
typedef __attribute__((ext_vector_type(4))) float fx4;
typedef unsigned short u16;
typedef unsigned int u32;
typedef unsigned char u8;

#define QK_SCALE 0.1803368801111204f  /* 0.125 * log2(e) */

#if __has_builtin(__builtin_amdgcn_exp2f)
#define EXP2(x) __builtin_amdgcn_exp2f(x)
#else
#define EXP2(x) exp2f(x)
#endif

static __device__ __forceinline__ u16 f2bf(float f) {
    u32 u = __float_as_uint(f);
    u += 0x7fffu + ((u >> 16) & 1u);
    return (u16)(u >> 16);
}
static __device__ __forceinline__ float bf2f(u16 h) {
    return __uint_as_float(((u32)h) << 16);
}
// truncate-pack two f32 -> two bf16 in one v_perm (softmax cancels the common bias)
static __device__ __forceinline__ int packtrunc(float a, float b) {
    return (int)__builtin_amdgcn_perm(__float_as_uint(b), __float_as_uint(a), 0x07060302u);
}

static __device__ __forceinline__ fx4 mfma16(s4v a, s4v b, fx4 c) {
#if __has_builtin(__builtin_amdgcn_mfma_f32_16x16x16bf16_1k)
    return __builtin_amdgcn_mfma_f32_16x16x16bf16_1k(a, b, c, 0, 0, 0);
#elif __has_builtin(__builtin_amdgcn_mfma_f32_16x16x16_bf16)
    return __builtin_amdgcn_mfma_f32_16x16x16_bf16(a, b, c, 0, 0, 0);
#else
    asm("v_mfma_f32_16x16x16_bf16 %0, %1, %2, %3" : "=v"(c) : "v"(a), "v"(b), "v"(c));
    return c;
#endif
}

// ---------------- K1: qkv proj -> Qh (scaled hi/lo), Kh (hi/lo), Vt (transposed bf16) ----------------
__global__ __launch_bounds__(192) void qkv_proj_kernel(
    const float* __restrict__ X, const float* __restrict__ W,
    const float* __restrict__ bias,
    u16* __restrict__ Qh, u16* __restrict__ Kh, u16* __restrict__ Vt,
    u32* __restrict__ VtBoth)
{
    {
        const int gt = blockIdx.x * 192 + threadIdx.x;
        if (gt < 65536) {   // [buf2][bh32][kg128] regions x 8 ones-words
            const int region = gt >> 3, word = gt & 7;
            VtBoth[region * 128 + 64 + word] = 0x3f803f80u;
        }
    }
    __shared__ __align__(16) float xsT[64 * 12];
    const int row0 = blockIdx.x * 8;
    const int t = threadIdx.x;
    if (t < 64) {
        #pragma unroll
        for (int r = 0; r < 8; ++r)
            xsT[t * 12 + r] = X[(size_t)(row0 + r) * 64 + t];
    }
    __syncthreads();
    const int j = t;
    const float bj = bias[j];
    float acc[8];
    #pragma unroll
    for (int r = 0; r < 8; ++r) acc[r] = bj;
    #pragma unroll 4
    for (int k = 0; k < 64; ++k) {
        const float w = W[k * 192 + j];
        const float4 x0 = *(const float4*)&xsT[k * 12];
        const float4 x1 = *(const float4*)&xsT[k * 12 + 4];
        acc[0] = fmaf(x0.x, w, acc[0]);
        acc[1] = fmaf(x0.y, w, acc[1]);
        acc[2] = fmaf(x0.z, w, acc[2]);
        acc[3] = fmaf(x0.w, w, acc[3]);
        acc[4] = fmaf(x1.x, w, acc[4]);
        acc[5] = fmaf(x1.y, w, acc[5]);
        acc[6] = fmaf(x1.z, w, acc[6]);
        acc[7] = fmaf(x1.w, w, acc[7]);
    }
    const int c = j & 63;
    const int h = c >> 3, d = c & 7;
    #pragma unroll
    for (int r = 0; r < 8; ++r) {
        const int R = row0 + r;
        const int bi = R >> 11, i = R & 2047;
        const int bh = bi * 8 + h;
        const float v = acc[r];
        if (j < 64) {
            const float qs = v * QK_SCALE;
            const u16 hh = f2bf(qs);
            const u16 ll = f2bf(qs - bf2f(hh));
            u16* qp = Qh + ((size_t)(bh * 2048 + i)) * 16 + d;
            qp[0] = hh; qp[8] = ll;
        } else if (j < 128) {
            const u16 hh = f2bf(v);
            const u16 ll = f2bf(v - bf2f(hh));
            u16* kp = Kh + ((size_t)(bh * 128 + (i >> 4)) * 16 + (i & 15)) * 16 + d;
            kp[0] = hh; kp[8] = ll;
        } else {
            Vt[((size_t)(bh * 128 + (i >> 4)) * 16 + d) * 16 + (i & 15)] = f2bf(v);
        }
    }
}

// ---------------- MFMA attention v13: R12 structure + reps (diagnostic) ----------------
// reps>1 re-walks the key stream WITHOUT resetting acc: every partial (incl. the
// ones-row denominator) scales by reps, and a/l normalization cancels it exactly.
// Output identical; duration scales ~reps -> stage-1 dispatch enters rocprof top-5.
// grid (bh=32, qt=64), x=bh fastest (XCD-L2-optimal, R14 lesson). 8 blocks/CU,
// VGPR<=64 (lb 256,8). Wave w: keys [w*512,(w+1)*512), 32 segs, 2-seg prefetch.
__global__ __launch_bounds__(256, 8) void attn_mfma13_kernel(
    const u16* __restrict__ Qh, const u8* __restrict__ Khb,
    const u8* __restrict__ Vtb, float* __restrict__ M, int reps)
{
    __shared__ __align__(16) float Lr[4][2][64][4];   // [wave][qg][lane][4] = 8KB
    const int bh = blockIdx.x, qt = blockIdx.y;
    const int tid = threadIdx.x, w = tid >> 6, l = tid & 63;
    const int g = l >> 4, ql = l & 15;

    s8v bq[2];
    #pragma unroll
    for (int qg = 0; qg < 2; ++qg)
        bq[qg] = *(const s8v*)(Qh + ((size_t)(bh * 2048 + qt * 32 + qg * 16 + ql)) * 16
                               + (g >> 1) * 8);

    const size_t kvoff = (size_t)bh * 65536 + w * 16384;
    const u8* kb0 = Khb + kvoff + ql * 32 + (g & 1) * 16;
    const u8* vb0 = Vtb + kvoff + ql * 32 + g * 8;

    fx4 acc[2];
    acc[0] = fx4{0.f, 0.f, 0.f, 0.f};
    acc[1] = fx4{0.f, 0.f, 0.f, 0.f};
    const fx4 zf = {0.f, 0.f, 0.f, 0.f};

#define PROCESS(KA, VA)                                                         \
    {                                                                           \
        _Pragma("unroll")                                                       \
        for (int qg = 0; qg < 2; ++qg) {                                        \
            fx4 s = __builtin_amdgcn_mfma_f32_16x16x32_bf16(KA, bq[qg], zf, 0, 0, 0); \
            union { int i2[2]; s4v v; } bp;                                     \
            bp.i2[0] = packtrunc(EXP2(s[0]), EXP2(s[1]));                       \
            bp.i2[1] = packtrunc(EXP2(s[2]), EXP2(s[3]));                       \
            acc[qg] = mfma16(VA, bp.v, acc[qg]);                                \
        }                                                                       \
    }

    #pragma unroll 1
    for (int rep = 0; rep < reps; ++rep) {
        const u8* kb = kb0;
        const u8* vb = vb0;
        s8v k0 = *(const s8v*)(kb);
        s8v k1 = *(const s8v*)(kb + 512);
        s4v v0 = *(const s4v*)(vb);
        s4v v1 = *(const s4v*)(vb + 512);
        #pragma unroll 1
        for (int it = 0; it < 16; ++it) {
            const s8v k2 = *(const s8v*)(kb + 1024);
            const s4v v2 = *(const s4v*)(vb + 1024);
            const s8v k3 = *(const s8v*)(kb + 1536);
            const s4v v3 = *(const s4v*)(vb + 1536);
            kb += 1024; vb += 1024;
            PROCESS(k0, v0);
            PROCESS(k1, v1);
            k0 = k2; v0 = v2; k1 = k3; v1 = v3;
        }
    }
#undef PROCESS

    // cross-wave reduction over key-quarters
    *(fx4*)&Lr[w][0][l][0] = acc[0];
    *(fx4*)&Lr[w][1][l][0] = acc[1];
    __syncthreads();

    if (w < 2) {                                   // wave w finalizes qg=w
        fx4 fin = {0.f, 0.f, 0.f, 0.f};
        #pragma unroll
        for (int wp = 0; wp < 4; ++wp) {
            const fx4 v = *(const fx4*)&Lr[wp][w][l][0];
            fin[0] += v[0]; fin[1] += v[1]; fin[2] += v[2]; fin[3] += v[3];
        }
        // denominator = O^T row 8 = lanes 32..47 (g==2, reg 0), col q
        const int lv_i = __builtin_amdgcn_ds_bpermute((32 + ql) * 4, __float_as_int(fin[0]));
        const float inv = 1.0f / __int_as_float(lv_i);
        if (g < 2) {
            const int qglob = qt * 32 + w * 16 + ql;
            const int b = bh >> 3, h = bh & 7;
            const float4 o = {fin[0] * inv, fin[1] * inv, fin[2] * inv, fin[3] * inv};
            *(float4*)(M + ((size_t)(b * 2048 + qglob)) * 64 + h * 8 + g * 4) = o;
        }
    }
}

// ---------------- proj64: mode 0 -> stage-2 Qh/Kh/Vt buffers; mode 1 -> plain f32 out ----------------
// q1 reshape: p-row rr, col c -> bh=bi*8+(rr>>8), key=(rr&255)*8+(c>>3), d=c&7
__global__ __launch_bounds__(64) void proj64_kernel(
    const float* __restrict__ X, const float* __restrict__ W,
    const float* __restrict__ bias,
    u16* __restrict__ Qh, u16* __restrict__ Kh, u16* __restrict__ Vt,
    float* __restrict__ Out, int mode)
{
    __shared__ __align__(16) float xsT[64 * 12];
    const int row0 = blockIdx.x * 8;
    const int c = threadIdx.x;
    #pragma unroll
    for (int r = 0; r < 8; ++r)
        xsT[c * 12 + r] = X[(size_t)(row0 + r) * 64 + c];
    __syncthreads();
    const float bc = bias[c];
    float acc[8];
    #pragma unroll
    for (int r = 0; r < 8; ++r) acc[r] = bc;
    #pragma unroll 4
    for (int k = 0; k < 64; ++k) {
        const float w = W[k * 64 + c];
        const float4 x0 = *(const float4*)&xsT[k * 12];
        const float4 x1 = *(const float4*)&xsT[k * 12 + 4];
        acc[0] = fmaf(x0.x, w, acc[0]);
        acc[1] = fmaf(x0.y, w, acc[1]);
        acc[2] = fmaf(x0.z, w, acc[2]);
        acc[3] = fmaf(x0.w, w, acc[3]);
        acc[4] = fmaf(x1.x, w, acc[4]);
        acc[5] = fmaf(x1.y, w, acc[5]);
        acc[6] = fmaf(x1.z, w, acc[6]);
        acc[7] = fmaf(x1.w, w, acc[7]);
    }
    if (mode == 0) {
        #pragma unroll
        for (int r = 0; r < 8; ++r) {
            const int R = row0 + r;
            const int bi = R >> 11, rr = R & 2047;
            const int bh = bi * 8 + (rr >> 8);
            const int key = (rr & 255) * 8 + (c >> 3);
            const int d = c & 7;
            const int kg = key >> 4, kr = key & 15;
            const float p = acc[r];
            const float qs = p * QK_SCALE;
            const u16 qh = f2bf(qs);
            const u16 qlo = f2bf(qs - bf2f(qh));
            const u16 kh = f2bf(p);
            const u16 kl = f2bf(p - bf2f(kh));
            u16* qp = Qh + ((size_t)(bh * 2048 + key)) * 16 + d;
            qp[0] = qh; qp[8] = qlo;
            u16* kp = Kh + ((size_t)(bh * 128 + kg) * 16 + kr) * 16 + d;
            kp[0] = kh; kp[8] = kl;
            Vt[((size_t)(bh * 128 + kg) * 16 + d) * 16 + kr] = f2bf(p);
        }
    } else {
        #pragma unroll
        for (int r = 0; r < 8; ++r)
            Out[(size_t)(row0 + r) * 64 + c] = acc[r];
    }
}

extern "C" void kernel_launch(void* const* d_in, const int* in_sizes, int n_in,
                              void* d_out, int out_size, void* d_ws, size_t ws_size,
                              hipStream_t stream) {
    const float* x    = (const float*)d_in[0];
    const float* Wqkv = (const float*)d_in[1];
    const float* bqkv = (const float*)d_in[2];
    const float* W1   = (const float*)d_in[3];
    const float* b1   = (const float*)d_in[4];
    float* out = (float*)d_out;
    u8* w8 = (u8*)d_ws;

    // byte layout (14 MiB used)
    u16*   Qh0  = (u16*)(w8);                       // 2 MiB
    u16*   Kh0  = (u16*)(w8 + (2u << 20));          // 2 MiB
    u16*   Vt0  = (u16*)(w8 + (4u << 20));          // 2 MiB
    u16*   Vt1  = (u16*)(w8 + (6u << 20));          // 2 MiB (adjacent to Vt0 for init)
    u16*   Qh1  = (u16*)(w8 + (8u << 20));          // 2 MiB
    u16*   Kh1  = (u16*)(w8 + (10u << 20));         // 2 MiB
    float* M1   = (float*)(w8 + (12u << 20));       // 2 MiB
    float* M2   = (float*)(w8);                     // overlays Qh0 (dead by then)

    qkv_proj_kernel<<<1024, 192, 0, stream>>>(x, Wqkv, bqkv, Qh0, Kh0, Vt0, (u32*)Vt0);
    // DIAGNOSTIC: stage-1 attn runs the key loop twice (output invariant: acc and
    // denominator both double; a/l cancels). ~57us -> enters rocprof top-5.
    attn_mfma13_kernel<<<dim3(32, 64), 256, 0, stream>>>(Qh0, (const u8*)Kh0, (const u8*)Vt0, M1, 2);
    proj64_kernel<<<1024, 64, 0, stream>>>(M1, W1, b1, Qh1, Kh1, Vt1, nullptr, 0);
    attn_mfma13_kernel<<<dim3(32, 64), 256, 0, stream>>>(Qh1, (const u8*)Kh1, (const u8*)Vt1, M2, 1);
    proj64_kernel<<<1024, 64, 0, stream>>>(M2, W1, b1, nullptr, nullptr, nullptr, out, 1);
}

// Round 17
// 63.195 us; speedup vs baseline: 1.3107x; 1.3107x over previous
//
#include <hip/hip_runtime.h>

typedef __attribute__((ext_vector_type(8))) short s8v;
typedef __attribute__((ext_vector_type(4))) short s4v;
typedef __attribute__((ext_vector_type(4))) float fx4;
typedef unsigned short u16;
typedef unsigned int u32;
typedef unsigned char u8;

#define QK_SCALE 0.1803368801111204f  /* 0.125 * log2(e) */

#if __has_builtin(__builtin_amdgcn_exp2f)
#define EXP2(x) __builtin_amdgcn_exp2f(x)
#else
#define EXP2(x) exp2f(x)
#endif

static __device__ __forceinline__ u16 f2bf(float f) {
    u32 u = __float_as_uint(f);
    u += 0x7fffu + ((u >> 16) & 1u);
    return (u16)(u >> 16);
}
static __device__ __forceinline__ float bf2f(u16 h) {
    return __uint_as_float(((u32)h) << 16);
}
// truncate-pack two f32 -> two bf16 in one v_perm (softmax cancels the common bias)
static __device__ __forceinline__ int packtrunc(float a, float b) {
    return (int)__builtin_amdgcn_perm(__float_as_uint(b), __float_as_uint(a), 0x07060302u);
}

static __device__ __forceinline__ fx4 mfma16(s4v a, s4v b, fx4 c) {
#if __has_builtin(__builtin_amdgcn_mfma_f32_16x16x16bf16_1k)
    return __builtin_amdgcn_mfma_f32_16x16x16bf16_1k(a, b, c, 0, 0, 0);
#elif __has_builtin(__builtin_amdgcn_mfma_f32_16x16x16_bf16)
    return __builtin_amdgcn_mfma_f32_16x16x16_bf16(a, b, c, 0, 0, 0);
#else
    asm("v_mfma_f32_16x16x16_bf16 %0, %1, %2, %3" : "=v"(c) : "v"(a), "v"(b), "v"(c));
    return c;
#endif
}

// ---------------- K1: qkv proj (4 rows/block, 2048 blocks -> 24 waves/CU) ----------------
// Writes Qh (scaled hi/lo), Kh (hi/lo), Vt (transposed bf16); inits ones-row of Vt0+Vt1.
__global__ __launch_bounds__(192) void qkv_proj_kernel(
    const float* __restrict__ X, const float* __restrict__ W,
    const float* __restrict__ bias,
    u16* __restrict__ Qh, u16* __restrict__ Kh, u16* __restrict__ Vt,
    u32* __restrict__ VtBoth)
{
    {
        const int gt = blockIdx.x * 192 + threadIdx.x;
        if (gt < 65536) {   // [buf2][bh32][kg128] regions x 8 ones-words
            const int region = gt >> 3, word = gt & 7;
            VtBoth[region * 128 + 64 + word] = 0x3f803f80u;
        }
    }
    __shared__ __align__(16) float xsT[64 * 8];   // [k][r], stride 8, float4-aligned
    const int row0 = blockIdx.x * 4;
    const int t = threadIdx.x;
    if (t < 64) {
        float4 xv;
        xv.x = X[(size_t)(row0 + 0) * 64 + t];
        xv.y = X[(size_t)(row0 + 1) * 64 + t];
        xv.z = X[(size_t)(row0 + 2) * 64 + t];
        xv.w = X[(size_t)(row0 + 3) * 64 + t];
        *(float4*)&xsT[t * 8] = xv;
    }
    __syncthreads();
    const int j = t;
    const float bj = bias[j];
    float a0 = bj, a1 = bj, a2 = bj, a3 = bj;
    #pragma unroll 8
    for (int k = 0; k < 64; ++k) {
        const float w = W[k * 192 + j];
        const float4 x = *(const float4*)&xsT[k * 8];   // broadcast read
        a0 = fmaf(x.x, w, a0);
        a1 = fmaf(x.y, w, a1);
        a2 = fmaf(x.z, w, a2);
        a3 = fmaf(x.w, w, a3);
    }
    const int c = j & 63;
    const int h = c >> 3, d = c & 7;
    const float accv[4] = {a0, a1, a2, a3};
    #pragma unroll
    for (int r = 0; r < 4; ++r) {
        const int R = row0 + r;
        const int bi = R >> 11, i = R & 2047;
        const int bh = bi * 8 + h;
        const float v = accv[r];
        if (j < 64) {
            const float qs = v * QK_SCALE;
            const u16 hh = f2bf(qs);
            const u16 ll = f2bf(qs - bf2f(hh));
            u16* qp = Qh + ((size_t)(bh * 2048 + i)) * 16 + d;
            qp[0] = hh; qp[8] = ll;
        } else if (j < 128) {
            const u16 hh = f2bf(v);
            const u16 ll = f2bf(v - bf2f(hh));
            u16* kp = Kh + ((size_t)(bh * 128 + (i >> 4)) * 16 + (i & 15)) * 16 + d;
            kp[0] = hh; kp[8] = ll;
        } else {
            Vt[((size_t)(bh * 128 + (i >> 4)) * 16 + d) * 16 + (i & 15)] = f2bf(v);
        }
    }
}

// ---------------- MFMA attention v12 (R15-proven): 8 waves/SIMD, XCD-local grid ----------------
// grid (bh=32, qt=64), x=bh fastest: XCD k gets bh===k (mod 8) -> 512KB K/V per XCD L2.
// Block: 32 q x 2048 keys. Wave w: keys [w*512,(w+1)*512), 32 segs, 2-seg prefetch,
// pointer-bump. setprio(1) on compute. QK: mfma_16x16x32 hi/lo; P=exp2 -> packtrunc ->
// B-frag 16x16x16; PV + ones-row denominator; ds_bpermute broadcast; normalized write.
__global__ __launch_bounds__(256, 8) void attn_mfma12_kernel(
    const u16* __restrict__ Qh, const u8* __restrict__ Khb,
    const u8* __restrict__ Vtb, float* __restrict__ M)
{
    __shared__ __align__(16) float Lr[4][2][64][4];   // [wave][qg][lane][4] = 8KB
    const int bh = blockIdx.x, qt = blockIdx.y;
    const int tid = threadIdx.x, w = tid >> 6, l = tid & 63;
    const int g = l >> 4, ql = l & 15;

    s8v bq[2];
    #pragma unroll
    for (int qg = 0; qg < 2; ++qg)
        bq[qg] = *(const s8v*)(Qh + ((size_t)(bh * 2048 + qt * 32 + qg * 16 + ql)) * 16
                               + (g >> 1) * 8);

    const size_t kvoff = (size_t)bh * 65536 + w * 16384;
    const u8* kb = Khb + kvoff + ql * 32 + (g & 1) * 16;
    const u8* vb = Vtb + kvoff + ql * 32 + g * 8;

    fx4 acc[2];
    acc[0] = fx4{0.f, 0.f, 0.f, 0.f};
    acc[1] = fx4{0.f, 0.f, 0.f, 0.f};
    const fx4 zf = {0.f, 0.f, 0.f, 0.f};

    s8v k0 = *(const s8v*)(kb);
    s8v k1 = *(const s8v*)(kb + 512);
    s4v v0 = *(const s4v*)(vb);
    s4v v1 = *(const s4v*)(vb + 512);

#define PROCESS(KA, VA)                                                         \
    {                                                                           \
        _Pragma("unroll")                                                       \
        for (int qg = 0; qg < 2; ++qg) {                                        \
            fx4 s = __builtin_amdgcn_mfma_f32_16x16x32_bf16(KA, bq[qg], zf, 0, 0, 0); \
            union { int i2[2]; s4v v; } bp;                                     \
            bp.i2[0] = packtrunc(EXP2(s[0]), EXP2(s[1]));                       \
            bp.i2[1] = packtrunc(EXP2(s[2]), EXP2(s[3]));                       \
            acc[qg] = mfma16(VA, bp.v, acc[qg]);                                \
        }                                                                       \
    }

    #pragma unroll 1
    for (int it = 0; it < 16; ++it) {
        const s8v k2 = *(const s8v*)(kb + 1024);
        const s4v v2 = *(const s4v*)(vb + 1024);
        const s8v k3 = *(const s8v*)(kb + 1536);
        const s4v v3 = *(const s4v*)(vb + 1536);
        kb += 1024; vb += 1024;
        __builtin_amdgcn_s_setprio(1);
        PROCESS(k0, v0);
        PROCESS(k1, v1);
        __builtin_amdgcn_s_setprio(0);
        k0 = k2; v0 = v2; k1 = k3; v1 = v3;
    }
#undef PROCESS

    // cross-wave reduction over key-quarters
    *(fx4*)&Lr[w][0][l][0] = acc[0];
    *(fx4*)&Lr[w][1][l][0] = acc[1];
    __syncthreads();

    if (w < 2) {                                   // wave w finalizes qg=w
        fx4 fin = {0.f, 0.f, 0.f, 0.f};
        #pragma unroll
        for (int wp = 0; wp < 4; ++wp) {
            const fx4 v = *(const fx4*)&Lr[wp][w][l][0];
            fin[0] += v[0]; fin[1] += v[1]; fin[2] += v[2]; fin[3] += v[3];
        }
        // denominator = O^T row 8 = lanes 32..47 (g==2, reg 0), col q
        const int lv_i = __builtin_amdgcn_ds_bpermute((32 + ql) * 4, __float_as_int(fin[0]));
        const float inv = 1.0f / __int_as_float(lv_i);
        if (g < 2) {
            const int qglob = qt * 32 + w * 16 + ql;
            const int b = bh >> 3, h = bh & 7;
            const float4 o = {fin[0] * inv, fin[1] * inv, fin[2] * inv, fin[3] * inv};
            *(float4*)(M + ((size_t)(b * 2048 + qglob)) * 64 + h * 8 + g * 4) = o;
        }
    }
}

// ---------------- proj64 (4 rows/block, 2048 blocks -> 8 waves/CU) ----------------
// mode 0 -> stage-2 Qh/Kh/Vt buffers; mode 1 -> plain f32 out.
// q1 reshape: p-row rr, col c -> bh=bi*8+(rr>>8), key=(rr&255)*8+(c>>3), d=c&7
__global__ __launch_bounds__(64) void proj64_kernel(
    const float* __restrict__ X, const float* __restrict__ W,
    const float* __restrict__ bias,
    u16* __restrict__ Qh, u16* __restrict__ Kh, u16* __restrict__ Vt,
    float* __restrict__ Out, int mode)
{
    __shared__ __align__(16) float xsT[64 * 8];   // [k][r], stride 8, float4-aligned
    const int row0 = blockIdx.x * 4;
    const int c = threadIdx.x;
    {
        float4 xv;
        xv.x = X[(size_t)(row0 + 0) * 64 + c];
        xv.y = X[(size_t)(row0 + 1) * 64 + c];
        xv.z = X[(size_t)(row0 + 2) * 64 + c];
        xv.w = X[(size_t)(row0 + 3) * 64 + c];
        *(float4*)&xsT[c * 8] = xv;
    }
    __syncthreads();
    const float bc = bias[c];
    float a0 = bc, a1 = bc, a2 = bc, a3 = bc;
    #pragma unroll 8
    for (int k = 0; k < 64; ++k) {
        const float w = W[k * 64 + c];
        const float4 x = *(const float4*)&xsT[k * 8];   // broadcast read
        a0 = fmaf(x.x, w, a0);
        a1 = fmaf(x.y, w, a1);
        a2 = fmaf(x.z, w, a2);
        a3 = fmaf(x.w, w, a3);
    }
    const float accv[4] = {a0, a1, a2, a3};
    if (mode == 0) {
        #pragma unroll
        for (int r = 0; r < 4; ++r) {
            const int R = row0 + r;
            const int bi = R >> 11, rr = R & 2047;
            const int bh = bi * 8 + (rr >> 8);
            const int key = (rr & 255) * 8 + (c >> 3);
            const int d = c & 7;
            const int kg = key >> 4, kr = key & 15;
            const float p = accv[r];
            const float qs = p * QK_SCALE;
            const u16 qh = f2bf(qs);
            const u16 qlo = f2bf(qs - bf2f(qh));
            const u16 kh = f2bf(p);
            const u16 kl = f2bf(p - bf2f(kh));
            u16* qp = Qh + ((size_t)(bh * 2048 + key)) * 16 + d;
            qp[0] = qh; qp[8] = qlo;
            u16* kp = Kh + ((size_t)(bh * 128 + kg) * 16 + kr) * 16 + d;
            kp[0] = kh; kp[8] = kl;
            Vt[((size_t)(bh * 128 + kg) * 16 + d) * 16 + kr] = f2bf(p);
        }
    } else {
        #pragma unroll
        for (int r = 0; r < 4; ++r)
            Out[(size_t)(row0 + r) * 64 + c] = accv[r];
    }
}

extern "C" void kernel_launch(void* const* d_in, const int* in_sizes, int n_in,
                              void* d_out, int out_size, void* d_ws, size_t ws_size,
                              hipStream_t stream) {
    const float* x    = (const float*)d_in[0];
    const float* Wqkv = (const float*)d_in[1];
    const float* bqkv = (const float*)d_in[2];
    const float* W1   = (const float*)d_in[3];
    const float* b1   = (const float*)d_in[4];
    float* out = (float*)d_out;
    u8* w8 = (u8*)d_ws;

    // byte layout (14 MiB used)
    u16*   Qh0  = (u16*)(w8);                       // 2 MiB
    u16*   Kh0  = (u16*)(w8 + (2u << 20));          // 2 MiB
    u16*   Vt0  = (u16*)(w8 + (4u << 20));          // 2 MiB
    u16*   Vt1  = (u16*)(w8 + (6u << 20));          // 2 MiB (adjacent to Vt0 for init)
    u16*   Qh1  = (u16*)(w8 + (8u << 20));          // 2 MiB
    u16*   Kh1  = (u16*)(w8 + (10u << 20));         // 2 MiB
    float* M1   = (float*)(w8 + (12u << 20));       // 2 MiB
    float* M2   = (float*)(w8);                     // overlays Qh0 (dead by then)

    qkv_proj_kernel<<<2048, 192, 0, stream>>>(x, Wqkv, bqkv, Qh0, Kh0, Vt0, (u32*)Vt0);
    attn_mfma12_kernel<<<dim3(32, 64), 256, 0, stream>>>(Qh0, (const u8*)Kh0, (const u8*)Vt0, M1);
    proj64_kernel<<<2048, 64, 0, stream>>>(M1, W1, b1, Qh1, Kh1, Vt1, nullptr, 0);
    attn_mfma12_kernel<<<dim3(32, 64), 256, 0, stream>>>(Qh1, (const u8*)Kh1, (const u8*)Vt1, M2);
    proj64_kernel<<<2048, 64, 0, stream>>>(M2, W1, b1, nullptr, nullptr, nullptr, out, 1);
}

// Round 18
// 59.251 us; speedup vs baseline: 1.3979x; 1.0666x over previous
//
#include <hip/hip_runtime.h>

typedef __attribute__((ext_vector_type(8))) short s8v;
typedef __attribute__((ext_vector_type(4))) short s4v;
typedef __attribute__((ext_vector_type(4))) float fx4;
typedef unsigned short u16;
typedef unsigned int u32;
typedef unsigned char u8;

#define QK_SCALE 0.1803368801111204f  /* 0.125 * log2(e) */

#if __has_builtin(__builtin_amdgcn_exp2f)
#define EXP2(x) __builtin_amdgcn_exp2f(x)
#else
#define EXP2(x) exp2f(x)
#endif

static __device__ __forceinline__ u16 f2bf(float f) {
    u32 u = __float_as_uint(f);
    u += 0x7fffu + ((u >> 16) & 1u);
    return (u16)(u >> 16);
}
static __device__ __forceinline__ float bf2f(u16 h) {
    return __uint_as_float(((u32)h) << 16);
}
// truncate-pack two f32 -> two bf16 in one v_perm (softmax cancels the common bias)
static __device__ __forceinline__ int packtrunc(float a, float b) {
    return (int)__builtin_amdgcn_perm(__float_as_uint(b), __float_as_uint(a), 0x07060302u);
}

static __device__ __forceinline__ fx4 mfma16(s4v a, s4v b, fx4 c) {
#if __has_builtin(__builtin_amdgcn_mfma_f32_16x16x16bf16_1k)
    return __builtin_amdgcn_mfma_f32_16x16x16bf16_1k(a, b, c, 0, 0, 0);
#elif __has_builtin(__builtin_amdgcn_mfma_f32_16x16x16_bf16)
    return __builtin_amdgcn_mfma_f32_16x16x16_bf16(a, b, c, 0, 0, 0);
#else
    asm("v_mfma_f32_16x16x16_bf16 %0, %1, %2, %3" : "=v"(c) : "v"(a), "v"(b), "v"(c));
    return c;
#endif
}

// ---------------- K1: qkv proj (4 rows/block, 2048 blocks) ----------------
// Qh: scaled hi/lo [bh][n][hi8|lo8]; Kh: HI-ONLY [bh][kg][16key][8d]; Vt transposed bf16.
// Inits ones-row of Vt0+Vt1.
__global__ __launch_bounds__(192) void qkv_proj_kernel(
    const float* __restrict__ X, const float* __restrict__ W,
    const float* __restrict__ bias,
    u16* __restrict__ Qh, u16* __restrict__ Kh, u16* __restrict__ Vt,
    u32* __restrict__ VtBoth)
{
    {
        const int gt = blockIdx.x * 192 + threadIdx.x;
        if (gt < 65536) {   // [buf2][bh32][kg128] regions x 8 ones-words
            const int region = gt >> 3, word = gt & 7;
            VtBoth[region * 128 + 64 + word] = 0x3f803f80u;
        }
    }
    __shared__ __align__(16) float xsT[64 * 8];   // [k][r], stride 8, float4-aligned
    const int row0 = blockIdx.x * 4;
    const int t = threadIdx.x;
    if (t < 64) {
        float4 xv;
        xv.x = X[(size_t)(row0 + 0) * 64 + t];
        xv.y = X[(size_t)(row0 + 1) * 64 + t];
        xv.z = X[(size_t)(row0 + 2) * 64 + t];
        xv.w = X[(size_t)(row0 + 3) * 64 + t];
        *(float4*)&xsT[t * 8] = xv;
    }
    __syncthreads();
    const int j = t;
    const float bj = bias[j];
    float a0 = bj, a1 = bj, a2 = bj, a3 = bj;
    #pragma unroll 8
    for (int k = 0; k < 64; ++k) {
        const float w = W[k * 192 + j];
        const float4 x = *(const float4*)&xsT[k * 8];   // broadcast read
        a0 = fmaf(x.x, w, a0);
        a1 = fmaf(x.y, w, a1);
        a2 = fmaf(x.z, w, a2);
        a3 = fmaf(x.w, w, a3);
    }
    const int c = j & 63;
    const int h = c >> 3, d = c & 7;
    const float accv[4] = {a0, a1, a2, a3};
    #pragma unroll
    for (int r = 0; r < 4; ++r) {
        const int R = row0 + r;
        const int bi = R >> 11, i = R & 2047;
        const int bh = bi * 8 + h;
        const float v = accv[r];
        if (j < 64) {
            const float qs = v * QK_SCALE;
            const u16 hh = f2bf(qs);
            const u16 ll = f2bf(qs - bf2f(hh));
            u16* qp = Qh + ((size_t)(bh * 2048 + i)) * 16 + d;
            qp[0] = hh; qp[8] = ll;
        } else if (j < 128) {
            Kh[((size_t)(bh * 128 + (i >> 4)) * 16 + (i & 15)) * 8 + d] = f2bf(v);
        } else {
            Vt[((size_t)(bh * 128 + (i >> 4)) * 16 + d) * 16 + (i & 15)] = f2bf(v);
        }
    }
}

// ---------------- MFMA attention v14: K hi-only, QK = 16x16x16 ----------------
// grid (bh=32, qt=64), x=bh fastest (XCD-L2-local). 8 blocks/CU, VGPR<=64 (lb 256,8).
// Block: 32 q x 2048 keys. Wave w: keys [w*512,(w+1)*512), 32 segs, 2-seg prefetch.
// QK 16x16x16: A lane(key=ql, g) = Khi d[4(g&1)..+3]; B = [qhi03,qhi47,qlo03,qlo47][g]
//   -> S = Khi·(Qhi+Qlo) (dropped Klo terms = K's bf16-RNE rounding, ~2^-9 rel).
// C: col=q=l&15, row=key=4g+r (same as before). P=exp2 -> packtrunc -> B-frag 16x16x16.
// PV + ones-row denominator; ds_bpermute broadcast; normalized write in-kernel.
__global__ __launch_bounds__(256, 8) void attn_mfma14_kernel(
    const u16* __restrict__ Qh, const u8* __restrict__ Khb,
    const u8* __restrict__ Vtb, float* __restrict__ M)
{
    __shared__ __align__(16) float Lr[4][2][64][4];   // [wave][qg][lane][4] = 8KB
    const int bh = blockIdx.x, qt = blockIdx.y;
    const int tid = threadIdx.x, w = tid >> 6, l = tid & 63;
    const int g = l >> 4, ql = l & 15;

    s4v bq[2];
    #pragma unroll
    for (int qg = 0; qg < 2; ++qg)
        bq[qg] = *(const s4v*)(Qh + ((size_t)(bh * 2048 + qt * 32 + qg * 16 + ql)) * 16
                               + g * 4);

    const u8* kb = Khb + (size_t)bh * 32768 + w * 8192 + ql * 16 + (g & 1) * 8;
    const u8* vb = Vtb + (size_t)bh * 65536 + w * 16384 + ql * 32 + g * 8;

    fx4 acc[2];
    acc[0] = fx4{0.f, 0.f, 0.f, 0.f};
    acc[1] = fx4{0.f, 0.f, 0.f, 0.f};
    const fx4 zf = {0.f, 0.f, 0.f, 0.f};

    s4v k0 = *(const s4v*)(kb);
    s4v k1 = *(const s4v*)(kb + 256);
    s4v v0 = *(const s4v*)(vb);
    s4v v1 = *(const s4v*)(vb + 512);

#define PROCESS(KA, VA)                                                         \
    {                                                                           \
        _Pragma("unroll")                                                       \
        for (int qg = 0; qg < 2; ++qg) {                                        \
            fx4 s = mfma16(KA, bq[qg], zf);                                     \
            union { int i2[2]; s4v v; } bp;                                     \
            bp.i2[0] = packtrunc(EXP2(s[0]), EXP2(s[1]));                       \
            bp.i2[1] = packtrunc(EXP2(s[2]), EXP2(s[3]));                       \
            acc[qg] = mfma16(VA, bp.v, acc[qg]);                                \
        }                                                                       \
    }

    #pragma unroll 1
    for (int it = 0; it < 16; ++it) {
        const s4v k2 = *(const s4v*)(kb + 512);
        const s4v v2 = *(const s4v*)(vb + 1024);
        const s4v k3 = *(const s4v*)(kb + 768);
        const s4v v3 = *(const s4v*)(vb + 1536);
        kb += 512; vb += 1024;
        __builtin_amdgcn_s_setprio(1);
        PROCESS(k0, v0);
        PROCESS(k1, v1);
        __builtin_amdgcn_s_setprio(0);
        k0 = k2; v0 = v2; k1 = k3; v1 = v3;
    }
#undef PROCESS

    // cross-wave reduction over key-quarters
    *(fx4*)&Lr[w][0][l][0] = acc[0];
    *(fx4*)&Lr[w][1][l][0] = acc[1];
    __syncthreads();

    if (w < 2) {                                   // wave w finalizes qg=w
        fx4 fin = {0.f, 0.f, 0.f, 0.f};
        #pragma unroll
        for (int wp = 0; wp < 4; ++wp) {
            const fx4 v = *(const fx4*)&Lr[wp][w][l][0];
            fin[0] += v[0]; fin[1] += v[1]; fin[2] += v[2]; fin[3] += v[3];
        }
        // denominator = O^T row 8 = lanes 32..47 (g==2, reg 0), col q
        const int lv_i = __builtin_amdgcn_ds_bpermute((32 + ql) * 4, __float_as_int(fin[0]));
        const float inv = 1.0f / __int_as_float(lv_i);
        if (g < 2) {
            const int qglob = qt * 32 + w * 16 + ql;
            const int b = bh >> 3, h = bh & 7;
            const float4 o = {fin[0] * inv, fin[1] * inv, fin[2] * inv, fin[3] * inv};
            *(float4*)(M + ((size_t)(b * 2048 + qglob)) * 64 + h * 8 + g * 4) = o;
        }
    }
}

// ---------------- proj64 (4 rows/block): mode 0 -> stage-2 buffers; mode 1 -> f32 out ----------------
// q1 reshape: p-row rr, col c -> bh=bi*8+(rr>>8), key=(rr&255)*8+(c>>3), d=c&7
__global__ __launch_bounds__(64) void proj64_kernel(
    const float* __restrict__ X, const float* __restrict__ W,
    const float* __restrict__ bias,
    u16* __restrict__ Qh, u16* __restrict__ Kh, u16* __restrict__ Vt,
    float* __restrict__ Out, int mode)
{
    __shared__ __align__(16) float xsT[64 * 8];   // [k][r], stride 8, float4-aligned
    const int row0 = blockIdx.x * 4;
    const int c = threadIdx.x;
    {
        float4 xv;
        xv.x = X[(size_t)(row0 + 0) * 64 + c];
        xv.y = X[(size_t)(row0 + 1) * 64 + c];
        xv.z = X[(size_t)(row0 + 2) * 64 + c];
        xv.w = X[(size_t)(row0 + 3) * 64 + c];
        *(float4*)&xsT[c * 8] = xv;
    }
    __syncthreads();
    const float bc = bias[c];
    float a0 = bc, a1 = bc, a2 = bc, a3 = bc;
    #pragma unroll 8
    for (int k = 0; k < 64; ++k) {
        const float w = W[k * 64 + c];
        const float4 x = *(const float4*)&xsT[k * 8];   // broadcast read
        a0 = fmaf(x.x, w, a0);
        a1 = fmaf(x.y, w, a1);
        a2 = fmaf(x.z, w, a2);
        a3 = fmaf(x.w, w, a3);
    }
    const float accv[4] = {a0, a1, a2, a3};
    if (mode == 0) {
        #pragma unroll
        for (int r = 0; r < 4; ++r) {
            const int R = row0 + r;
            const int bi = R >> 11, rr = R & 2047;
            const int bh = bi * 8 + (rr >> 8);
            const int key = (rr & 255) * 8 + (c >> 3);
            const int d = c & 7;
            const int kg = key >> 4, kr = key & 15;
            const float p = accv[r];
            const float qs = p * QK_SCALE;
            const u16 qh = f2bf(qs);
            const u16 qlo = f2bf(qs - bf2f(qh));
            u16* qp = Qh + ((size_t)(bh * 2048 + key)) * 16 + d;
            qp[0] = qh; qp[8] = qlo;
            Kh[((size_t)(bh * 128 + kg) * 16 + kr) * 8 + d] = f2bf(p);
            Vt[((size_t)(bh * 128 + kg) * 16 + d) * 16 + kr] = f2bf(p);
        }
    } else {
        #pragma unroll
        for (int r = 0; r < 4; ++r)
            Out[(size_t)(row0 + r) * 64 + c] = accv[r];
    }
}

extern "C" void kernel_launch(void* const* d_in, const int* in_sizes, int n_in,
                              void* d_out, int out_size, void* d_ws, size_t ws_size,
                              hipStream_t stream) {
    const float* x    = (const float*)d_in[0];
    const float* Wqkv = (const float*)d_in[1];
    const float* bqkv = (const float*)d_in[2];
    const float* W1   = (const float*)d_in[3];
    const float* b1   = (const float*)d_in[4];
    float* out = (float*)d_out;
    u8* w8 = (u8*)d_ws;

    // byte layout (14 MiB reserved; Kh now 1 MiB each, slots kept at 2 MiB)
    u16*   Qh0  = (u16*)(w8);                       // 2 MiB
    u16*   Kh0  = (u16*)(w8 + (2u << 20));          // 1 MiB used
    u16*   Vt0  = (u16*)(w8 + (4u << 20));          // 2 MiB
    u16*   Vt1  = (u16*)(w8 + (6u << 20));          // 2 MiB (adjacent to Vt0 for init)
    u16*   Qh1  = (u16*)(w8 + (8u << 20));          // 2 MiB
    u16*   Kh1  = (u16*)(w8 + (10u << 20));         // 1 MiB used
    float* M1   = (float*)(w8 + (12u << 20));       // 2 MiB
    float* M2   = (float*)(w8);                     // overlays Qh0 (dead by then)

    qkv_proj_kernel<<<2048, 192, 0, stream>>>(x, Wqkv, bqkv, Qh0, Kh0, Vt0, (u32*)Vt0);
    attn_mfma14_kernel<<<dim3(32, 64), 256, 0, stream>>>(Qh0, (const u8*)Kh0, (const u8*)Vt0, M1);
    proj64_kernel<<<2048, 64, 0, stream>>>(M1, W1, b1, Qh1, Kh1, Vt1, nullptr, 0);
    attn_mfma14_kernel<<<dim3(32, 64), 256, 0, stream>>>(Qh1, (const u8*)Kh1, (const u8*)Vt1, M2);
    proj64_kernel<<<2048, 64, 0, stream>>>(M2, W1, b1, nullptr, nullptr, nullptr, out, 1);
}